// Round 11
// baseline (151.578 us; speedup 1.0000x reference)
//
#include <hip/hip_runtime.h>

constexpr int N_  = 64;
constexpr int C_  = 256;
constexpr int HW_ = 56 * 56;      // 3136 floats per slice
constexpr int NV_ = HW_ / 4;      // 784 f32x4 per slice
constexpr int G_  = 32;
constexpr int NC_ = N_ * C_;      // 16384
constexpr float EPS_ = 1e-5f;

typedef float f32x4 __attribute__((ext_vector_type(4)));

// ---------------- Kernel 1: per-(n,c) sum & sumsq — one wave per slice (r5, proven) ----------------
__global__ __launch_bounds__(256) void k_sums(const float* __restrict__ x,
                                              float* __restrict__ s1,
                                              float* __restrict__ s2) {
    const int wave = threadIdx.x >> 6;
    const int lane = threadIdx.x & 63;
    const int nc = blockIdx.x * 4 + wave;
    const f32x4* xp = reinterpret_cast<const f32x4*>(x + (size_t)nc * HW_);
    f32x4 v[12];
    #pragma unroll
    for (int k = 0; k < 12; ++k) v[k] = xp[lane + k * 64];
    f32x4 vt;
    const bool tail = lane < 16;
    if (tail) vt = xp[768 + lane];
    float a = 0.f, b = 0.f;
    #pragma unroll
    for (int k = 0; k < 12; ++k) {
        a += (v[k].x + v[k].y) + (v[k].z + v[k].w);
        b += (v[k].x * v[k].x + v[k].y * v[k].y) + (v[k].z * v[k].z + v[k].w * v[k].w);
    }
    if (tail) {
        a += (vt.x + vt.y) + (vt.z + vt.w);
        b += (vt.x * vt.x + vt.y * vt.y) + (vt.z * vt.z + vt.w * vt.w);
    }
    #pragma unroll
    for (int off = 32; off; off >>= 1) {
        a += __shfl_down(a, off, 64);
        b += __shfl_down(b, off, 64);
    }
    if (lane == 0) { s1[nc] = a; s2[nc] = b; }
}

// ---------------- Kernel 2 (merged middle): logits+argmax+group stats -> scale/shift ----------------
// 64 blocks (one per n) x 256 threads (one per channel). Every block computes ALL
// channels' logits with identical FP order -> identical argmax in every block
// (deterministic). fc_w staged transposed in LDS; s1/s2 reads are coalesced.
__global__ __launch_bounds__(256) void k_mid(const float* __restrict__ s1,
                                             const float* __restrict__ s2,
                                             const float* __restrict__ fc_w,
                                             const float* __restrict__ fc_b,
                                             const float* __restrict__ weight,
                                             const float* __restrict__ bias,
                                             float* __restrict__ scale,
                                             float* __restrict__ shift) {
    const int n = blockIdx.x;
    const int t = threadIdx.x;           // t == channel c

    __shared__ float wT[2 * N_ * G_];    // wT[nn*32+g] = fc_w[g*128+nn], 16 KiB
    __shared__ float bL[G_];
    __shared__ float r1s[C_], r2s[C_];
    __shared__ int   gi[C_];
    __shared__ float mg[G_], ig[G_];

    for (int i = t; i < 2 * N_ * G_; i += 256) {
        const int nn = i >> 5, g = i & (G_ - 1);
        wT[i] = fc_w[g * (2 * N_) + nn];
    }
    if (t < G_) bL[t] = fc_b[t];
    __syncthreads();

    const float inv_hw  = 1.f / (float)HW_;
    const float inv_hw1 = 1.f / (float)(HW_ - 1);

    float acc[G_];
    #pragma unroll
    for (int g = 0; g < G_; ++g) acc[g] = bL[g];
    float myr1 = 0.f, myr2 = 0.f;

    for (int nn = 0; nn < N_; ++nn) {
        const float v1 = s1[nn * C_ + t];    // coalesced across threads
        const float v2 = s2[nn * C_ + t];
        const float m  = v1 * inv_hw;
        const float vr = (v2 - v1 * m) * inv_hw1;   // ddof=1
        if (nn == n) { myr1 = v1; myr2 = v2; }
        const float* w1 = &wT[nn * G_];
        const float* w2 = &wT[(N_ + nn) * G_];
        #pragma unroll
        for (int g = 0; g < G_; ++g)
            acc[g] += m * w1[g] + vr * w2[g];       // LDS broadcast reads
    }

    // first-occurrence argmax over g (matches jnp.argmax)
    float best = acc[0]; int bi = 0;
    #pragma unroll
    for (int g = 1; g < G_; ++g)
        if (acc[g] > best) { best = acc[g]; bi = g; }

    gi[t]  = bi;
    r1s[t] = myr1;
    r2s[t] = myr2;
    __syncthreads();

    if (t < G_) {
        float A = 0.f, B = 0.f; int k = 0;
        for (int cc = 0; cc < C_; ++cc)
            if (gi[cc] == t) { A += r1s[cc]; B += r2s[cc]; ++k; }
        const float cf = (float)k * (float)HW_;
        const float m  = A / fmaxf(cf, 1.f);
        const float vr = (B - A * m) / fmaxf(cf - 1.f, 1.f);
        mg[t] = m;
        ig[t] = rsqrtf(vr + EPS_);
    }
    __syncthreads();

    const int g = gi[t];
    const float sc = ig[g] * weight[t];
    scale[n * C_ + t] = sc;
    shift[n * C_ + t] = bias[t] - mg[g] * sc;
}

// ---------------- Kernel 3: normalize — one wave per slice (r5, proven) ----------------
// Regular loads for x, NT stores for out (never re-read; don't pollute L3).
__global__ __launch_bounds__(256) void k_norm(const float* __restrict__ x,
                                              const float* __restrict__ scale,
                                              const float* __restrict__ shift,
                                              float* __restrict__ out) {
    const int wave = threadIdx.x >> 6;
    const int lane = threadIdx.x & 63;
    const int nc = blockIdx.x * 4 + wave;
    const float sc = scale[nc];
    const float sh = shift[nc];
    const f32x4* xp = reinterpret_cast<const f32x4*>(x + (size_t)nc * HW_);
    f32x4* op = reinterpret_cast<f32x4*>(out + (size_t)nc * HW_);
    f32x4 v[12];
    #pragma unroll
    for (int k = 0; k < 12; ++k) v[k] = xp[lane + k * 64];
    f32x4 vt;
    const bool tail = lane < 16;
    if (tail) vt = xp[768 + lane];
    #pragma unroll
    for (int k = 0; k < 12; ++k)
        __builtin_nontemporal_store(v[k] * sc + sh, op + lane + k * 64);
    if (tail)
        __builtin_nontemporal_store(vt * sc + sh, op + 768 + lane);
}

extern "C" void kernel_launch(void* const* d_in, const int* in_sizes, int n_in,
                              void* d_out, int out_size, void* d_ws, size_t ws_size,
                              hipStream_t stream) {
    const float* x      = (const float*)d_in[0];
    const float* fc_w   = (const float*)d_in[1];
    const float* fc_b   = (const float*)d_in[2];
    const float* weight = (const float*)d_in[3];
    const float* bias   = (const float*)d_in[4];
    float* outp = (float*)d_out;

    float* ws    = (float*)d_ws;
    float* s1    = ws;
    float* s2    = ws + NC_;
    float* scale = ws + 2 * NC_;
    float* shift = ws + 3 * NC_;

    k_sums<<<NC_ / 4, 256, 0, stream>>>(x, s1, s2);
    k_mid <<<N_,      256, 0, stream>>>(s1, s2, fc_w, fc_b, weight, bias, scale, shift);
    k_norm<<<NC_ / 4, 256, 0, stream>>>(x, scale, shift, outp);
}

// Round 12
// 120.339 us; speedup vs baseline: 1.2596x; 1.2596x over previous
//
#include <hip/hip_runtime.h>

constexpr int N_  = 64;
constexpr int C_  = 256;
constexpr int HW_ = 56 * 56;      // 3136 floats per slice
constexpr int G_  = 32;
constexpr int NC_ = N_ * C_;      // 16384
constexpr float EPS_ = 1e-5f;

typedef float f32x4 __attribute__((ext_vector_type(4)));

// ---------------- Kernel 1: per-(n,c) sum & sumsq — one wave per slice ----------------
// Regular loads: this is the allocating read that leaves x L3-resident for k_norm.
__global__ __launch_bounds__(256) void k_sums(const float* __restrict__ x,
                                              float* __restrict__ s1,
                                              float* __restrict__ s2) {
    const int wave = threadIdx.x >> 6;
    const int lane = threadIdx.x & 63;
    const int nc = blockIdx.x * 4 + wave;
    const f32x4* xp = reinterpret_cast<const f32x4*>(x + (size_t)nc * HW_);
    f32x4 v[12];
    #pragma unroll
    for (int k = 0; k < 12; ++k) v[k] = xp[lane + k * 64];
    f32x4 vt;
    const bool tail = lane < 16;
    if (tail) vt = xp[768 + lane];
    float a = 0.f, b = 0.f;
    #pragma unroll
    for (int k = 0; k < 12; ++k) {
        a += (v[k].x + v[k].y) + (v[k].z + v[k].w);
        b += (v[k].x * v[k].x + v[k].y * v[k].y) + (v[k].z * v[k].z + v[k].w * v[k].w);
    }
    if (tail) {
        a += (vt.x + vt.y) + (vt.z + vt.w);
        b += (vt.x * vt.x + vt.y * vt.y) + (vt.z * vt.z + vt.w * vt.w);
    }
    #pragma unroll
    for (int off = 32; off; off >>= 1) {
        a += __shfl_down(a, off, 64);
        b += __shfl_down(b, off, 64);
    }
    if (lane == 0) { s1[nc] = a; s2[nc] = b; }
}

// ---------------- Kernel 2: per-channel logits + first-occurrence argmax ----------------
__global__ __launch_bounds__(64) void k_logits(const float* __restrict__ s1,
                                               const float* __restrict__ s2,
                                               const float* __restrict__ fc_w,
                                               const float* __restrict__ fc_b,
                                               int* __restrict__ gidx) {
    const int c = blockIdx.x;
    const int t = threadIdx.x;
    const int g = t & 31, half = t >> 5;
    const float inv_hw  = 1.f / (float)HW_;
    const float inv_hw1 = 1.f / (float)(HW_ - 1);
    const float* wg = fc_w + g * (2 * N_);
    float acc = half ? 0.f : fc_b[g];
    const int n0 = half * 32;
    #pragma unroll 8
    for (int n = n0; n < n0 + 32; ++n) {
        const float v1 = s1[n * C_ + c];
        const float v2 = s2[n * C_ + c];
        const float m  = v1 * inv_hw;
        const float vr = (v2 - v1 * m) * inv_hw1;   // ddof=1
        acc += m * wg[n] + vr * wg[N_ + n];
    }
    acc += __shfl_down(acc, 32, 64);
    __shared__ float lg[G_];
    if (half == 0) lg[g] = acc;
    __syncthreads();
    if (t == 0) {
        float best = lg[0];
        int bi = 0;
        for (int g2 = 1; g2 < G_; ++g2) {
            const float v = lg[g2];
            if (v > best) { best = v; bi = g2; }
        }
        gidx[c] = bi;
    }
}

// ---------------- Kernel 3: per-n group stats -> fused scale/shift ----------------
__global__ __launch_bounds__(256) void k_group(const float* __restrict__ s1,
                                               const float* __restrict__ s2,
                                               const int* __restrict__ gidx,
                                               const float* __restrict__ weight,
                                               const float* __restrict__ bias,
                                               float* __restrict__ scale,
                                               float* __restrict__ shift) {
    const int n = blockIdx.x;
    const int c = threadIdx.x;
    __shared__ float r1[C_], r2[C_];
    __shared__ int   gi[C_];
    __shared__ float mg[G_], ig[G_];
    r1[c] = s1[n * C_ + c];
    r2[c] = s2[n * C_ + c];
    gi[c] = gidx[c];
    __syncthreads();
    if (c < G_) {
        float A = 0.f, B = 0.f;
        int k = 0;
        for (int cc = 0; cc < C_; ++cc) {
            if (gi[cc] == c) { A += r1[cc]; B += r2[cc]; ++k; }
        }
        const float cf = (float)k * (float)HW_;
        const float m  = A / fmaxf(cf, 1.f);
        const float vr = (B - A * m) / fmaxf(cf - 1.f, 1.f);
        mg[c] = m;
        ig[c] = rsqrtf(vr + EPS_);
    }
    __syncthreads();
    const int g = gi[c];
    const float sc = ig[g] * weight[c];
    scale[n * C_ + c] = sc;
    shift[n * C_ + c] = bias[c] - mg[g] * sc;
}

// ---------------- Kernel 4: normalize — one wave per slice ----------------
// Regular loads for x (L3-warm from k_sums), NT stores for out (never re-read).
__global__ __launch_bounds__(256) void k_norm(const float* __restrict__ x,
                                              const float* __restrict__ scale,
                                              const float* __restrict__ shift,
                                              float* __restrict__ out) {
    const int wave = threadIdx.x >> 6;
    const int lane = threadIdx.x & 63;
    const int nc = blockIdx.x * 4 + wave;
    const float sc = scale[nc];
    const float sh = shift[nc];
    const f32x4* xp = reinterpret_cast<const f32x4*>(x + (size_t)nc * HW_);
    f32x4* op = reinterpret_cast<f32x4*>(out + (size_t)nc * HW_);
    f32x4 v[12];
    #pragma unroll
    for (int k = 0; k < 12; ++k) v[k] = xp[lane + k * 64];
    f32x4 vt;
    const bool tail = lane < 16;
    if (tail) vt = xp[768 + lane];
    #pragma unroll
    for (int k = 0; k < 12; ++k)
        __builtin_nontemporal_store(v[k] * sc + sh, op + lane + k * 64);
    if (tail)
        __builtin_nontemporal_store(vt * sc + sh, op + 768 + lane);
}

extern "C" void kernel_launch(void* const* d_in, const int* in_sizes, int n_in,
                              void* d_out, int out_size, void* d_ws, size_t ws_size,
                              hipStream_t stream) {
    const float* x      = (const float*)d_in[0];
    const float* fc_w   = (const float*)d_in[1];
    const float* fc_b   = (const float*)d_in[2];
    const float* weight = (const float*)d_in[3];
    const float* bias   = (const float*)d_in[4];
    float* outp = (float*)d_out;

    float* ws    = (float*)d_ws;
    float* s1    = ws;
    float* s2    = ws + NC_;
    float* scale = ws + 2 * NC_;
    float* shift = ws + 3 * NC_;
    int*   gidxg = (int*)(ws + 4 * NC_);

    k_sums  <<<NC_ / 4, 256, 0, stream>>>(x, s1, s2);
    k_logits<<<C_,       64, 0, stream>>>(s1, s2, fc_w, fc_b, gidxg);
    k_group <<<N_,      256, 0, stream>>>(s1, s2, gidxg, weight, bias, scale, shift);
    k_norm  <<<NC_ / 4, 256, 0, stream>>>(x, scale, shift, outp);
}